// Round 12
// baseline (657.174 us; speedup 1.0000x reference)
//
#include <hip/hip_runtime.h>
#include <hip/hip_bf16.h>

#define D 128
#define KT 32
#define SS_BLOCKS 256
#define NUM_BLOCKS 2048

__device__ __forceinline__ float bfl(unsigned u) { return __uint_as_float(u << 16); }
__device__ __forceinline__ float bfh(unsigned u) { return __uint_as_float(u & 0xffff0000u); }
__device__ __forceinline__ unsigned short f2b(float f) {
    unsigned u = __float_as_uint(f);
    return (unsigned short)((u + 0x7fffu + ((u >> 16) & 1u)) >> 16);
}

// ---------------- merged: f2bf (x -> bf16 table) + hist/deg/slot ----------------
__global__ __launch_bounds__(256) void pre_kernel(const float* __restrict__ x,
                                                  unsigned short* __restrict__ xh,
                                                  const int* __restrict__ src,
                                                  const int* __restrict__ dst,
                                                  const float* __restrict__ w,
                                                  int* __restrict__ cnt,
                                                  float* __restrict__ deg,
                                                  int* __restrict__ slot,
                                                  int E, int n8, int fGrid) {
    int b = blockIdx.x;
    if (b < fGrid) {
        int i = b * 256 + threadIdx.x;
        if (i < n8) {
            float4 a = ((const float4*)x)[2 * i];
            float4 c = ((const float4*)x)[2 * i + 1];
            ushort4 lo = make_ushort4(f2b(a.x), f2b(a.y), f2b(a.z), f2b(a.w));
            ushort4 hi = make_ushort4(f2b(c.x), f2b(c.y), f2b(c.z), f2b(c.w));
            ((ushort4*)xh)[2 * i] = lo;
            ((ushort4*)xh)[2 * i + 1] = hi;
        }
    } else {
        int e = (b - fGrid) * 256 + threadIdx.x;
        if (e < E) {
            slot[e] = atomicAdd(&cnt[dst[e]], 1);
            atomicAdd(&deg[src[e]], w[e]);
        }
    }
}

// ---------------- CSR build: per-1024-chunk inclusive scan ----------------
__global__ __launch_bounds__(256) void scan_chunk_kernel(const int* __restrict__ cnt,
                                                         int* __restrict__ rowptr,
                                                         int* __restrict__ aux, int N) {
    __shared__ int ts[256];
    int t = threadIdx.x;
    int base = blockIdx.x * 1024 + t * 4;
    int v[4], s = 0;
#pragma unroll
    for (int i = 0; i < 4; ++i) {
        v[i] = (base + i < N) ? cnt[base + i] : 0;
        s += v[i];
    }
    ts[t] = s;
    __syncthreads();
#pragma unroll
    for (int off = 1; off < 256; off <<= 1) {
        int add = (t >= off) ? ts[t - off] : 0;
        __syncthreads();
        ts[t] += add;
        __syncthreads();
    }
    int run = ts[t] - s;
#pragma unroll
    for (int i = 0; i < 4; ++i) {
        run += v[i];
        if (base + i < N) rowptr[base + i + 1] = run;
    }
    if (t == 255) aux[blockIdx.x] = ts[255];
}

__global__ void scan_aux_kernel(int* __restrict__ aux, int nb) {
    if (threadIdx.x == 0) {
        int s = 0;
        for (int i = 0; i < nb; ++i) { s += aux[i]; aux[i] = s; }
    }
}

__global__ __launch_bounds__(256) void add_off_kernel(int* __restrict__ rowptr,
                                                      const int* __restrict__ aux, int N) {
    int i = blockIdx.x * 256 + threadIdx.x;
    if (i == 0) rowptr[0] = 0;
    if (i < N) {
        int b = i >> 10;
        if (b > 0) rowptr[i + 1] += aux[b - 1];
    }
}

// ---------------- CSR fill: packed edge records epk = {src, w_bits} ----------------
__global__ __launch_bounds__(256) void fill_kernel(const int* __restrict__ src,
                                                   const int* __restrict__ dst,
                                                   const float* __restrict__ w,
                                                   const int* __restrict__ rowptr,
                                                   const int* __restrict__ slot,
                                                   int2* __restrict__ epk, int E) {
    int e = blockIdx.x * 256 + threadIdx.x;
    if (e < E) {
        int pos = rowptr[dst[e]] + slot[e];
        epk[pos] = make_int2(src[e], __float_as_int(w[e]));
    }
}

// ---------------- gather (bf16 rows): quarter-wave, 32 edges in flight ----------------
__global__ __launch_bounds__(256) void gatherq_kernel(const unsigned short* __restrict__ xh,
                                                      const int2* __restrict__ epk,
                                                      const int* __restrict__ rowptr,
                                                      float* __restrict__ agg, int N) {
    int node = blockIdx.x * 4 + (threadIdx.x >> 6);
    if (node >= N) return;
    int lane = threadIdx.x & 63;
    int q = lane >> 4;
    int c8 = (lane & 15) * 8;
    int beg = rowptr[node], end = rowptr[node + 1];
    float a[4][8];
#pragma unroll
    for (int i = 0; i < 4; ++i)
#pragma unroll
        for (int k = 0; k < 8; ++k) a[i][k] = 0.f;
    int j = beg;
    for (; j + 31 < end; j += 32) {
        int2 ed[8]; uint4 qv[8];
#pragma unroll
        for (int i = 0; i < 8; ++i) ed[i] = epk[j + 4 * i + q];
#pragma unroll
        for (int i = 0; i < 8; ++i) qv[i] = *(const uint4*)&xh[(size_t)ed[i].x * D + c8];
#pragma unroll
        for (int i = 0; i < 8; ++i) {
            float w0 = __int_as_float(ed[i].y);
            a[i & 3][0] += w0 * bfl(qv[i].x); a[i & 3][1] += w0 * bfh(qv[i].x);
            a[i & 3][2] += w0 * bfl(qv[i].y); a[i & 3][3] += w0 * bfh(qv[i].y);
            a[i & 3][4] += w0 * bfl(qv[i].z); a[i & 3][5] += w0 * bfh(qv[i].z);
            a[i & 3][6] += w0 * bfl(qv[i].w); a[i & 3][7] += w0 * bfh(qv[i].w);
        }
    }
    for (; j + 3 < end; j += 4) {
        int2 ed = epk[j + q];
        float w0 = __int_as_float(ed.y);
        uint4 qv = *(const uint4*)&xh[(size_t)ed.x * D + c8];
        a[0][0] += w0 * bfl(qv.x); a[0][1] += w0 * bfh(qv.x);
        a[0][2] += w0 * bfl(qv.y); a[0][3] += w0 * bfh(qv.y);
        a[0][4] += w0 * bfl(qv.z); a[0][5] += w0 * bfh(qv.z);
        a[0][6] += w0 * bfl(qv.w); a[0][7] += w0 * bfh(qv.w);
    }
    int rem = end - j;
    if (q < rem) {
        int2 ed = epk[j + q];
        float w0 = __int_as_float(ed.y);
        uint4 qv = *(const uint4*)&xh[(size_t)ed.x * D + c8];
        a[1][0] += w0 * bfl(qv.x); a[1][1] += w0 * bfh(qv.x);
        a[1][2] += w0 * bfl(qv.y); a[1][3] += w0 * bfh(qv.y);
        a[1][4] += w0 * bfl(qv.z); a[1][5] += w0 * bfh(qv.z);
        a[1][6] += w0 * bfl(qv.w); a[1][7] += w0 * bfh(qv.w);
    }
    float r[8];
#pragma unroll
    for (int k = 0; k < 8; ++k) {
        r[k] = a[0][k] + a[1][k] + a[2][k] + a[3][k];
        r[k] += __shfl_xor(r[k], 16);
        r[k] += __shfl_xor(r[k], 32);
    }
    if (lane < 16) {
        *(float4*)&agg[(size_t)node * D + c8]     = make_float4(r[0], r[1], r[2], r[3]);
        *(float4*)&agg[(size_t)node * D + c8 + 4] = make_float4(r[4], r[5], r[6], r[7]);
    }
}

// ---------------- GraphConv linear: out = relu(A1@W1 + A2@W2 + b) ----------------
#define FMA4(acc, a, wv) { acc.x += (a) * (wv).x; acc.y += (a) * (wv).y; \
                           acc.z += (a) * (wv).z; acc.w += (a) * (wv).w; }

__global__ __launch_bounds__(256) void lin_kernel(const float* __restrict__ A1,
                                                  const float* __restrict__ A2,
                                                  const float* __restrict__ W1,
                                                  const float* __restrict__ W2,
                                                  const float* __restrict__ b,
                                                  float* __restrict__ out,
                                                  unsigned short* __restrict__ outh, int N) {
    __shared__ float As[KT][132];
    __shared__ float Ws[KT][D];
    int tid = threadIdx.x;
    int r0 = blockIdx.x * 128;
    int ty4 = (tid >> 3) * 4;
    int tx16 = (tid & 7) * 16;

    float4 acc[4][4];
#pragma unroll
    for (int i = 0; i < 4; ++i)
#pragma unroll
        for (int j = 0; j < 4; ++j) acc[i][j] = make_float4(0.f, 0.f, 0.f, 0.f);

    for (int t = 0; t < 8; ++t) {
        const float* A = (t < 4) ? A1 : A2;
        const float* W = (t < 4) ? W1 : W2;
        int koff = (t & 3) * KT;
        __syncthreads();
#pragma unroll
        for (int i = 0; i < 4; ++i) {
            int f4 = tid + i * 256;
            int row = f4 >> 3;
            int c4 = f4 & 7;
            float4 v = make_float4(0.f, 0.f, 0.f, 0.f);
            if (r0 + row < N) v = *(const float4*)&A[(size_t)(r0 + row) * D + koff + c4 * 4];
            As[c4 * 4 + 0][row] = v.x;
            As[c4 * 4 + 1][row] = v.y;
            As[c4 * 4 + 2][row] = v.z;
            As[c4 * 4 + 3][row] = v.w;
        }
#pragma unroll
        for (int i = 0; i < 4; ++i) {
            int f4 = tid + i * 256;
            int k = f4 >> 5;
            int c4 = f4 & 31;
            *(float4*)&Ws[k][c4 * 4] = *(const float4*)&W[(size_t)(koff + k) * D + c4 * 4];
        }
        __syncthreads();
#pragma unroll 4
        for (int k = 0; k < KT; ++k) {
            float4 av = *(const float4*)&As[k][ty4];
            float4 w0 = *(const float4*)&Ws[k][tx16];
            float4 w1 = *(const float4*)&Ws[k][tx16 + 4];
            float4 w2 = *(const float4*)&Ws[k][tx16 + 8];
            float4 w3 = *(const float4*)&Ws[k][tx16 + 12];
            FMA4(acc[0][0], av.x, w0); FMA4(acc[0][1], av.x, w1);
            FMA4(acc[0][2], av.x, w2); FMA4(acc[0][3], av.x, w3);
            FMA4(acc[1][0], av.y, w0); FMA4(acc[1][1], av.y, w1);
            FMA4(acc[1][2], av.y, w2); FMA4(acc[1][3], av.y, w3);
            FMA4(acc[2][0], av.z, w0); FMA4(acc[2][1], av.z, w1);
            FMA4(acc[2][2], av.z, w2); FMA4(acc[2][3], av.z, w3);
            FMA4(acc[3][0], av.w, w0); FMA4(acc[3][1], av.w, w1);
            FMA4(acc[3][2], av.w, w2); FMA4(acc[3][3], av.w, w3);
        }
    }
    float4 bv[4];
#pragma unroll
    for (int j = 0; j < 4; ++j) bv[j] = *(const float4*)&b[tx16 + j * 4];
#pragma unroll
    for (int i = 0; i < 4; ++i) {
        int r = r0 + ty4 + i;
        if (r < N) {
#pragma unroll
            for (int j = 0; j < 4; ++j) {
                float4 v;
                v.x = fmaxf(acc[i][j].x + bv[j].x, 0.f);
                v.y = fmaxf(acc[i][j].y + bv[j].y, 0.f);
                v.z = fmaxf(acc[i][j].z + bv[j].z, 0.f);
                v.w = fmaxf(acc[i][j].w + bv[j].w, 0.f);
                *(float4*)&out[(size_t)r * D + tx16 + j * 4] = v;
                if (outh) {
                    ushort4 u = make_ushort4(f2b(v.x), f2b(v.y), f2b(v.z), f2b(v.w));
                    *(ushort4*)&outh[(size_t)r * D + tx16 + j * 4] = u;
                }
            }
        }
    }
}

// ---------------- Wc = W_m1 @ W_out ; bc = b_m1 @ W_out + b_out ----------------
__global__ __launch_bounds__(256) void smallmm_kernel(const float* __restrict__ Wm1,
                                                      const float* __restrict__ bm1,
                                                      const float* __restrict__ Wout,
                                                      const float* __restrict__ bout,
                                                      float* __restrict__ Wc,
                                                      float* __restrict__ bc) {
    int idx = blockIdx.x * 256 + threadIdx.x;
    if (blockIdx.x < 64) {
        int i = idx >> 7, j = idx & 127;
        float s = 0.f;
        for (int k = 0; k < 128; ++k) s += Wm1[i * 128 + k] * Wout[k * 128 + j];
        Wc[idx] = s;
    } else {
        int j = threadIdx.x;
        if (j < 128) {
            float s = bout[j];
            for (int k = 0; k < 128; ++k) s += bm1[k] * Wout[k * 128 + j];
            bc[j] = s;
        }
    }
}

// ---------------- s = h2@Wc + bc, softmax -> probs (+bf16 copy); den accum ----------------
__global__ __launch_bounds__(256) void out_softmax_kernel(const float* __restrict__ h2,
                                                          const float* __restrict__ Wc,
                                                          const float* __restrict__ bc,
                                                          const float* __restrict__ deg,
                                                          float* __restrict__ probs,
                                                          unsigned short* __restrict__ pbh,
                                                          float* __restrict__ accum, int N) {
    __shared__ float Rs[32][128];
    __shared__ float Ws[128 * 64];
    int tid = threadIdx.x;
    int wave = tid >> 6, lane = tid & 63;
    int r0 = blockIdx.x * 32;
#pragma unroll
    for (int i = 0; i < 4; ++i) {
        int f4 = tid + i * 256;
        int row = f4 >> 5;
        int c4 = f4 & 31;
        float4 v = make_float4(0.f, 0.f, 0.f, 0.f);
        if (r0 + row < N) v = *(const float4*)&h2[(size_t)(r0 + row) * D + c4 * 4];
        *(float4*)&Rs[row][c4 * 4] = v;
    }
    float lg[8][2];
#pragma unroll
    for (int h = 0; h < 2; ++h) {
        __syncthreads();
#pragma unroll
        for (int i = 0; i < 8; ++i) {
            int f4 = tid + i * 256;
            int k = f4 >> 4;
            int c4 = f4 & 15;
            *(float4*)&Ws[k * 64 + c4 * 4] = *(const float4*)&Wc[(size_t)k * 128 + h * 64 + c4 * 4];
        }
        __syncthreads();
        float bv = bc[h * 64 + lane];
        float a[8];
#pragma unroll
        for (int ri = 0; ri < 8; ++ri) a[ri] = bv;
        for (int k = 0; k < 128; ++k) {
            float wv = Ws[k * 64 + lane];
#pragma unroll
            for (int ri = 0; ri < 8; ++ri) a[ri] += Rs[wave + ri * 4][k] * wv;
        }
#pragma unroll
        for (int ri = 0; ri < 8; ++ri) lg[ri][h] = a[ri];
    }
    float den_local = 0.f;
#pragma unroll
    for (int ri = 0; ri < 8; ++ri) {
        int row = wave + ri * 4;
        int gr = r0 + row;
        float m = fmaxf(lg[ri][0], lg[ri][1]);
#pragma unroll
        for (int s = 32; s >= 1; s >>= 1) m = fmaxf(m, __shfl_xor(m, s));
        float e0 = expf(lg[ri][0] - m);
        float e1 = expf(lg[ri][1] - m);
        float sum = e0 + e1;
#pragma unroll
        for (int s = 32; s >= 1; s >>= 1) sum += __shfl_xor(sum, s);
        float inv = 1.f / sum;
        float p0 = e0 * inv, p1 = e1 * inv;
        float sq = p0 * p0 + p1 * p1;
#pragma unroll
        for (int s = 32; s >= 1; s >>= 1) sq += __shfl_xor(sq, s);
        if (gr < N) {
            probs[(size_t)gr * D + lane]      = p0;
            probs[(size_t)gr * D + 64 + lane] = p1;
            pbh[(size_t)gr * D + lane]      = f2b(p0);
            pbh[(size_t)gr * D + 64 + lane] = f2b(p1);
            if (lane == 0) den_local += deg[gr] * sq;
        }
    }
    if (lane == 0 && den_local != 0.f) atomicAdd(&accum[1], den_local);
}

// ---------------- merged: ss partials (blocks [0,SS_BLOCKS)) + mincut_num (rest) ----------------
__global__ __launch_bounds__(256) void num_ss_kernel(const float* __restrict__ probs,
                                                     const unsigned short* __restrict__ pbh,
                                                     const int2* __restrict__ epk,
                                                     const int* __restrict__ rowptr,
                                                     float* __restrict__ accum,
                                                     float* __restrict__ partial, int N) {
    int tid = threadIdx.x;
    if (blockIdx.x < SS_BLOCKS) {
        __shared__ float Ps[32][132];
        int a0 = (tid >> 4) * 8;
        int b0 = (tid & 15) * 8;
        float acc[8][8];
#pragma unroll
        for (int i = 0; i < 8; ++i)
#pragma unroll
            for (int j = 0; j < 8; ++j) acc[i][j] = 0.f;

        int rowsPerBlk = (N + SS_BLOCKS - 1) / SS_BLOCKS;
        int rbeg = blockIdx.x * rowsPerBlk;
        int rend = rbeg + rowsPerBlk;
        if (rend > N) rend = N;

        for (int c = rbeg; c < rend; c += 32) {
            int nr = rend - c;
            if (nr > 32) nr = 32;
            __syncthreads();
            for (int i = tid; i < nr * 32; i += 256) {
                int r = i >> 5, c4 = i & 31;
                *(float4*)&Ps[r][c4 * 4] = *(const float4*)&probs[(size_t)(c + r) * D + c4 * 4];
            }
            __syncthreads();
            for (int r = 0; r < nr; ++r) {
                float4 av0 = *(const float4*)&Ps[r][a0];
                float4 av1 = *(const float4*)&Ps[r][a0 + 4];
                float4 bv0 = *(const float4*)&Ps[r][b0];
                float4 bv1 = *(const float4*)&Ps[r][b0 + 4];
                float av[8] = {av0.x, av0.y, av0.z, av0.w, av1.x, av1.y, av1.z, av1.w};
                float bv[8] = {bv0.x, bv0.y, bv0.z, bv0.w, bv1.x, bv1.y, bv1.z, bv1.w};
#pragma unroll
                for (int i = 0; i < 8; ++i)
#pragma unroll
                    for (int j = 0; j < 8; ++j) acc[i][j] += av[i] * bv[j];
            }
        }
        float* pb = partial + (size_t)blockIdx.x * 16384;
#pragma unroll
        for (int i = 0; i < 8; ++i) {
            *(float4*)&pb[(a0 + i) * 128 + b0]     = make_float4(acc[i][0], acc[i][1], acc[i][2], acc[i][3]);
            *(float4*)&pb[(a0 + i) * 128 + b0 + 4] = make_float4(acc[i][4], acc[i][5], acc[i][6], acc[i][7]);
        }
        return;
    }
    // ---- num part: 32 edges in flight ----
    int bid = blockIdx.x - SS_BLOCKS;
    int wave = tid >> 6, lane = tid & 63;
    int q = lane >> 4;
    int c8 = (lane & 15) * 8;
    float acc = 0.f;
    int stride = NUM_BLOCKS * 4;
    for (int node = bid * 4 + wave; node < N; node += stride) {
        float4 pdA = *(const float4*)&probs[(size_t)node * D + c8];
        float4 pdB = *(const float4*)&probs[(size_t)node * D + c8 + 4];
        int beg = rowptr[node], end = rowptr[node + 1];
        int j = beg;
        for (; j + 31 < end; j += 32) {
            int2 ed[8]; uint4 qv[8];
#pragma unroll
            for (int i = 0; i < 8; ++i) ed[i] = epk[j + 4 * i + q];
#pragma unroll
            for (int i = 0; i < 8; ++i) qv[i] = *(const uint4*)&pbh[(size_t)ed[i].x * D + c8];
#pragma unroll
            for (int i = 0; i < 8; ++i) {
                float w0 = __int_as_float(ed[i].y);
                acc += w0 * (bfl(qv[i].x) * pdA.x + bfh(qv[i].x) * pdA.y
                           + bfl(qv[i].y) * pdA.z + bfh(qv[i].y) * pdA.w
                           + bfl(qv[i].z) * pdB.x + bfh(qv[i].z) * pdB.y
                           + bfl(qv[i].w) * pdB.z + bfh(qv[i].w) * pdB.w);
            }
        }
        for (; j + 3 < end; j += 4) {
            int2 ed = epk[j + q];
            float w0 = __int_as_float(ed.y);
            uint4 qv = *(const uint4*)&pbh[(size_t)ed.x * D + c8];
            acc += w0 * (bfl(qv.x) * pdA.x + bfh(qv.x) * pdA.y
                       + bfl(qv.y) * pdA.z + bfh(qv.y) * pdA.w
                       + bfl(qv.z) * pdB.x + bfh(qv.z) * pdB.y
                       + bfl(qv.w) * pdB.z + bfh(qv.w) * pdB.w);
        }
        int rem = end - j;
        if (q < rem) {
            int2 ed = epk[j + q];
            float w0 = __int_as_float(ed.y);
            uint4 qv = *(const uint4*)&pbh[(size_t)ed.x * D + c8];
            acc += w0 * (bfl(qv.x) * pdA.x + bfh(qv.x) * pdA.y
                       + bfl(qv.y) * pdA.z + bfh(qv.y) * pdA.w
                       + bfl(qv.z) * pdB.x + bfh(qv.z) * pdB.y
                       + bfl(qv.w) * pdB.z + bfh(qv.w) * pdB.w);
        }
    }
#pragma unroll
    for (int m = 32; m >= 1; m >>= 1) acc += __shfl_xor(acc, m);
    if (lane == 0 && acc != 0.f) atomicAdd(&accum[0], acc);
}

// ---------------- reduce partials -> ss ----------------
__global__ __launch_bounds__(256) void ss_reduce_kernel(const float* __restrict__ partial,
                                                        float* __restrict__ ss) {
    int i = blockIdx.x * 256 + threadIdx.x;
    float s = 0.f;
    for (int b = 0; b < SS_BLOCKS; ++b) s += partial[(size_t)b * 16384 + i];
    ss[i] = s;
}

// ---------------- finalize: mc_loss, o_loss ----------------
__global__ __launch_bounds__(256) void finalize_kernel(const float* __restrict__ ss,
                                                       const float* __restrict__ accum,
                                                       float* __restrict__ out2) {
    int tid = threadIdx.x;
    __shared__ float wsum[4], wsum2[4];
    float s = 0.f;
    for (int i = tid; i < 16384; i += 256) { float v = ss[i]; s += v * v; }
#pragma unroll
    for (int m = 32; m >= 1; m >>= 1) s += __shfl_xor(s, m);
    if ((tid & 63) == 0) wsum[tid >> 6] = s;
    __syncthreads();
    float norm = sqrtf(wsum[0] + wsum[1] + wsum[2] + wsum[3]);
    float inv = 1.f / norm;
    const float rk = 0.08838834764831845f;  // 1/sqrt(128)
    float o = 0.f;
    for (int i = tid; i < 16384; i += 256) {
        int a = i >> 7, b = i & 127;
        float v = ss[i] * inv - (a == b ? rk : 0.f);
        o += v * v;
    }
#pragma unroll
    for (int m = 32; m >= 1; m >>= 1) o += __shfl_xor(o, m);
    if ((tid & 63) == 0) wsum2[tid >> 6] = o;
    __syncthreads();
    if (tid == 0) {
        out2[0] = -(accum[0] / accum[1]);
        out2[1] = sqrtf(wsum2[0] + wsum2[1] + wsum2[2] + wsum2[3]);
    }
}

extern "C" void kernel_launch(void* const* d_in, const int* in_sizes, int n_in,
                              void* d_out, int out_size, void* d_ws, size_t ws_size,
                              hipStream_t stream) {
    const float* x      = (const float*)d_in[0];
    const int*   ei     = (const int*)d_in[1];
    const float* w      = (const float*)d_in[2];
    const float* Wrel1  = (const float*)d_in[3];
    const float* brel1  = (const float*)d_in[4];
    const float* Wroot1 = (const float*)d_in[5];
    const float* Wrel2  = (const float*)d_in[6];
    const float* brel2  = (const float*)d_in[7];
    const float* Wroot2 = (const float*)d_in[8];
    const float* Wm1    = (const float*)d_in[9];
    const float* bm1    = (const float*)d_in[10];
    const float* Wout   = (const float*)d_in[11];
    const float* bout   = (const float*)d_in[12];

    int N = in_sizes[0] / D;
    int E = in_sizes[2];
    const int* src = ei;
    const int* dst = ei + E;

    float* probs = (float*)d_out;
    float* out2  = probs + (size_t)N * D;  // [mc_loss, o_loss]
    float* h2    = probs;                  // h2 in-place in d_out

    float* ws    = (float*)d_ws;
    float* agg   = ws;                       // N*D  (reused as ss partials)
    float* h1    = ws + (size_t)N * D;       // N*D  (aliases xh pre-lin1)
    float* Wc    = ws + (size_t)2 * N * D;   // 16384
    float* bc    = Wc + 16384;               // 128
    float* ssb   = bc + 128;                 // 16384
    float* deg   = ssb + 16384;              // N
    float* accum = deg + N;                  // 2
    int2*  epk   = (int2*)(accum + 2);       // E int2 (packed src, w)
    int*   cnt   = (int*)(epk + E);          // N
    int*   rowptr= cnt + N;                  // N+1
    int*   aux   = rowptr + N + 1;           // 64
    int*   slot  = aux + 64;                 // E
    // pbh double-duty: h1-bf16 table (lin1 -> gatherq2), then probs-bf16
    // (out_softmax -> num). Live ranges don't overlap.
    unsigned short* pbh = (unsigned short*)(slot + E);  // N*D bf16
    unsigned short* xh  = (unsigned short*)h1;          // N*D bf16 (h1 dead pre-lin1)

    hipMemsetAsync(deg, 0, (size_t)(N + 2) * sizeof(float), stream);
    hipMemsetAsync(cnt, 0, (size_t)N * sizeof(int), stream);

    int eGrid = (E + 255) / 256;
    int nb = (N + 1023) / 1024;
    int n8 = N * D / 8;
    int fGrid = (n8 + 255) / 256;

    // merged f2bf + hist/deg/slot
    pre_kernel<<<fGrid + eGrid, 256, 0, stream>>>(x, xh, src, dst, w, cnt, deg, slot,
                                                  E, n8, fGrid);
    scan_chunk_kernel<<<nb, 256, 0, stream>>>(cnt, rowptr, aux, N);
    scan_aux_kernel<<<1, 64, 0, stream>>>(aux, nb);
    add_off_kernel<<<(N + 255) / 256, 256, 0, stream>>>(rowptr, aux, N);
    fill_kernel<<<eGrid, 256, 0, stream>>>(src, dst, w, rowptr, slot, epk, E);

    // layer 1: bf16 gather + linear (emits h1 fp32 + h1 bf16 table into pbh)
    gatherq_kernel<<<(N + 3) / 4, 256, 0, stream>>>(xh, epk, rowptr, agg, N);
    lin_kernel<<<(N + 127) / 128, 256, 0, stream>>>(agg, x, Wrel1, Wroot1, brel1,
                                                    h1, pbh, N);
    // layer 2: bf16 gather (pbh as h1-bf16) + linear (h2 in-place in probs)
    gatherq_kernel<<<(N + 3) / 4, 256, 0, stream>>>(pbh, epk, rowptr, agg, N);
    lin_kernel<<<(N + 127) / 128, 256, 0, stream>>>(agg, h1, Wrel2, Wroot2, brel2,
                                                    h2, (unsigned short*)nullptr, N);
    smallmm_kernel<<<65, 256, 0, stream>>>(Wm1, bm1, Wout, bout, Wc, bc);
    out_softmax_kernel<<<(N + 31) / 32, 256, 0, stream>>>(h2, Wc, bc, deg, probs, pbh, accum, N);
    num_ss_kernel<<<SS_BLOCKS + NUM_BLOCKS, 256, 0, stream>>>(probs, pbh, epk,
                                                              rowptr, accum, agg, N);
    ss_reduce_kernel<<<64, 256, 0, stream>>>(agg, ssb);
    finalize_kernel<<<1, 256, 0, stream>>>(ssb, accum, out2);
}

// Round 13
// 619.799 us; speedup vs baseline: 1.0603x; 1.0603x over previous
//
#include <hip/hip_runtime.h>
#include <hip/hip_bf16.h>

#define D 128
#define KT 32
#define SS_BLOCKS 256
#define NUM_BLOCKS 2048

__device__ __forceinline__ float bfl(unsigned u) { return __uint_as_float(u << 16); }
__device__ __forceinline__ float bfh(unsigned u) { return __uint_as_float(u & 0xffff0000u); }
__device__ __forceinline__ unsigned short f2b(float f) {
    unsigned u = __float_as_uint(f);
    return (unsigned short)((u + 0x7fffu + ((u >> 16) & 1u)) >> 16);
}

// ---------------- merged: f2bf (x -> bf16 table) + hist/deg/slot ----------------
__global__ __launch_bounds__(256) void pre_kernel(const float* __restrict__ x,
                                                  unsigned short* __restrict__ xh,
                                                  const int* __restrict__ src,
                                                  const int* __restrict__ dst,
                                                  const float* __restrict__ w,
                                                  int* __restrict__ cnt,
                                                  float* __restrict__ deg,
                                                  int* __restrict__ slot,
                                                  int E, int n8, int fGrid) {
    int b = blockIdx.x;
    if (b < fGrid) {
        int i = b * 256 + threadIdx.x;
        if (i < n8) {
            float4 a = ((const float4*)x)[2 * i];
            float4 c = ((const float4*)x)[2 * i + 1];
            ushort4 lo = make_ushort4(f2b(a.x), f2b(a.y), f2b(a.z), f2b(a.w));
            ushort4 hi = make_ushort4(f2b(c.x), f2b(c.y), f2b(c.z), f2b(c.w));
            ((ushort4*)xh)[2 * i] = lo;
            ((ushort4*)xh)[2 * i + 1] = hi;
        }
    } else {
        int e = (b - fGrid) * 256 + threadIdx.x;
        if (e < E) {
            slot[e] = atomicAdd(&cnt[dst[e]], 1);
            atomicAdd(&deg[src[e]], w[e]);
        }
    }
}

// ---------------- CSR build: per-1024-chunk inclusive scan ----------------
__global__ __launch_bounds__(256) void scan_chunk_kernel(const int* __restrict__ cnt,
                                                         int* __restrict__ rowptr,
                                                         int* __restrict__ aux, int N) {
    __shared__ int ts[256];
    int t = threadIdx.x;
    int base = blockIdx.x * 1024 + t * 4;
    int v[4], s = 0;
#pragma unroll
    for (int i = 0; i < 4; ++i) {
        v[i] = (base + i < N) ? cnt[base + i] : 0;
        s += v[i];
    }
    ts[t] = s;
    __syncthreads();
#pragma unroll
    for (int off = 1; off < 256; off <<= 1) {
        int add = (t >= off) ? ts[t - off] : 0;
        __syncthreads();
        ts[t] += add;
        __syncthreads();
    }
    int run = ts[t] - s;
#pragma unroll
    for (int i = 0; i < 4; ++i) {
        run += v[i];
        if (base + i < N) rowptr[base + i + 1] = run;
    }
    if (t == 255) aux[blockIdx.x] = ts[255];
}

__global__ void scan_aux_kernel(int* __restrict__ aux, int nb) {
    if (threadIdx.x == 0) {
        int s = 0;
        for (int i = 0; i < nb; ++i) { s += aux[i]; aux[i] = s; }
    }
}

__global__ __launch_bounds__(256) void add_off_kernel(int* __restrict__ rowptr,
                                                      const int* __restrict__ aux, int N) {
    int i = blockIdx.x * 256 + threadIdx.x;
    if (i == 0) rowptr[0] = 0;
    if (i < N) {
        int b = i >> 10;
        if (b > 0) rowptr[i + 1] += aux[b - 1];
    }
}

// ---------------- CSR fill (atomic-free: slot from pre) ----------------
__global__ __launch_bounds__(256) void fill_kernel(const int* __restrict__ src,
                                                   const int* __restrict__ dst,
                                                   const float* __restrict__ w,
                                                   const int* __restrict__ rowptr,
                                                   const int* __restrict__ slot,
                                                   int* __restrict__ csr_src,
                                                   float* __restrict__ csr_w, int E) {
    int e = blockIdx.x * 256 + threadIdx.x;
    if (e < E) {
        int pos = rowptr[dst[e]] + slot[e];
        csr_src[pos] = src[e];
        csr_w[pos] = w[e];
    }
}

// ---------------- gather (bf16 rows): quarter-wave, 16 edges in flight ----------------
__global__ __launch_bounds__(256) void gatherq_kernel(const unsigned short* __restrict__ xh,
                                                      const int* __restrict__ csr_src,
                                                      const float* __restrict__ csr_w,
                                                      const int* __restrict__ rowptr,
                                                      float* __restrict__ agg, int N) {
    int node = blockIdx.x * 4 + (threadIdx.x >> 6);
    if (node >= N) return;
    int lane = threadIdx.x & 63;
    int q = lane >> 4;
    int c8 = (lane & 15) * 8;
    int beg = rowptr[node], end = rowptr[node + 1];
    float a[4][8];
#pragma unroll
    for (int i = 0; i < 4; ++i)
#pragma unroll
        for (int k = 0; k < 8; ++k) a[i][k] = 0.f;
    int j = beg;
    for (; j + 15 < end; j += 16) {
        int si[4]; float wi[4]; uint4 qv[4];
#pragma unroll
        for (int i = 0; i < 4; ++i) {
            int e = j + 4 * i + q;
            si[i] = csr_src[e];
            wi[i] = csr_w[e];
        }
#pragma unroll
        for (int i = 0; i < 4; ++i) qv[i] = *(const uint4*)&xh[(size_t)si[i] * D + c8];
#pragma unroll
        for (int i = 0; i < 4; ++i) {
            a[i][0] += wi[i] * bfl(qv[i].x); a[i][1] += wi[i] * bfh(qv[i].x);
            a[i][2] += wi[i] * bfl(qv[i].y); a[i][3] += wi[i] * bfh(qv[i].y);
            a[i][4] += wi[i] * bfl(qv[i].z); a[i][5] += wi[i] * bfh(qv[i].z);
            a[i][6] += wi[i] * bfl(qv[i].w); a[i][7] += wi[i] * bfh(qv[i].w);
        }
    }
    for (; j + 3 < end; j += 4) {
        int e = j + q;
        int s0 = csr_src[e]; float w0 = csr_w[e];
        uint4 qv = *(const uint4*)&xh[(size_t)s0 * D + c8];
        a[0][0] += w0 * bfl(qv.x); a[0][1] += w0 * bfh(qv.x);
        a[0][2] += w0 * bfl(qv.y); a[0][3] += w0 * bfh(qv.y);
        a[0][4] += w0 * bfl(qv.z); a[0][5] += w0 * bfh(qv.z);
        a[0][6] += w0 * bfl(qv.w); a[0][7] += w0 * bfh(qv.w);
    }
    int rem = end - j;
    if (q < rem) {
        int e = j + q;
        int s0 = csr_src[e]; float w0 = csr_w[e];
        uint4 qv = *(const uint4*)&xh[(size_t)s0 * D + c8];
        a[1][0] += w0 * bfl(qv.x); a[1][1] += w0 * bfh(qv.x);
        a[1][2] += w0 * bfl(qv.y); a[1][3] += w0 * bfh(qv.y);
        a[1][4] += w0 * bfl(qv.z); a[1][5] += w0 * bfh(qv.z);
        a[1][6] += w0 * bfl(qv.w); a[1][7] += w0 * bfh(qv.w);
    }
    float r[8];
#pragma unroll
    for (int k = 0; k < 8; ++k) {
        r[k] = a[0][k] + a[1][k] + a[2][k] + a[3][k];
        r[k] += __shfl_xor(r[k], 16);
        r[k] += __shfl_xor(r[k], 32);
    }
    if (lane < 16) {
        *(float4*)&agg[(size_t)node * D + c8]     = make_float4(r[0], r[1], r[2], r[3]);
        *(float4*)&agg[(size_t)node * D + c8 + 4] = make_float4(r[4], r[5], r[6], r[7]);
    }
}

// ---------------- GraphConv linear: out = relu(A1@W1 + A2@W2 + b) ----------------
#define FMA4(acc, a, wv) { acc.x += (a) * (wv).x; acc.y += (a) * (wv).y; \
                           acc.z += (a) * (wv).z; acc.w += (a) * (wv).w; }

__global__ __launch_bounds__(256) void lin_kernel(const float* __restrict__ A1,
                                                  const float* __restrict__ A2,
                                                  const float* __restrict__ W1,
                                                  const float* __restrict__ W2,
                                                  const float* __restrict__ b,
                                                  float* __restrict__ out,
                                                  unsigned short* __restrict__ outh, int N) {
    __shared__ float As[KT][132];
    __shared__ float Ws[KT][D];
    int tid = threadIdx.x;
    int r0 = blockIdx.x * 128;
    int ty4 = (tid >> 3) * 4;
    int tx16 = (tid & 7) * 16;

    float4 acc[4][4];
#pragma unroll
    for (int i = 0; i < 4; ++i)
#pragma unroll
        for (int j = 0; j < 4; ++j) acc[i][j] = make_float4(0.f, 0.f, 0.f, 0.f);

    for (int t = 0; t < 8; ++t) {
        const float* A = (t < 4) ? A1 : A2;
        const float* W = (t < 4) ? W1 : W2;
        int koff = (t & 3) * KT;
        __syncthreads();
#pragma unroll
        for (int i = 0; i < 4; ++i) {
            int f4 = tid + i * 256;
            int row = f4 >> 3;
            int c4 = f4 & 7;
            float4 v = make_float4(0.f, 0.f, 0.f, 0.f);
            if (r0 + row < N) v = *(const float4*)&A[(size_t)(r0 + row) * D + koff + c4 * 4];
            As[c4 * 4 + 0][row] = v.x;
            As[c4 * 4 + 1][row] = v.y;
            As[c4 * 4 + 2][row] = v.z;
            As[c4 * 4 + 3][row] = v.w;
        }
#pragma unroll
        for (int i = 0; i < 4; ++i) {
            int f4 = tid + i * 256;
            int k = f4 >> 5;
            int c4 = f4 & 31;
            *(float4*)&Ws[k][c4 * 4] = *(const float4*)&W[(size_t)(koff + k) * D + c4 * 4];
        }
        __syncthreads();
#pragma unroll 4
        for (int k = 0; k < KT; ++k) {
            float4 av = *(const float4*)&As[k][ty4];
            float4 w0 = *(const float4*)&Ws[k][tx16];
            float4 w1 = *(const float4*)&Ws[k][tx16 + 4];
            float4 w2 = *(const float4*)&Ws[k][tx16 + 8];
            float4 w3 = *(const float4*)&Ws[k][tx16 + 12];
            FMA4(acc[0][0], av.x, w0); FMA4(acc[0][1], av.x, w1);
            FMA4(acc[0][2], av.x, w2); FMA4(acc[0][3], av.x, w3);
            FMA4(acc[1][0], av.y, w0); FMA4(acc[1][1], av.y, w1);
            FMA4(acc[1][2], av.y, w2); FMA4(acc[1][3], av.y, w3);
            FMA4(acc[2][0], av.z, w0); FMA4(acc[2][1], av.z, w1);
            FMA4(acc[2][2], av.z, w2); FMA4(acc[2][3], av.z, w3);
            FMA4(acc[3][0], av.w, w0); FMA4(acc[3][1], av.w, w1);
            FMA4(acc[3][2], av.w, w2); FMA4(acc[3][3], av.w, w3);
        }
    }
    float4 bv[4];
#pragma unroll
    for (int j = 0; j < 4; ++j) bv[j] = *(const float4*)&b[tx16 + j * 4];
#pragma unroll
    for (int i = 0; i < 4; ++i) {
        int r = r0 + ty4 + i;
        if (r < N) {
#pragma unroll
            for (int j = 0; j < 4; ++j) {
                float4 v;
                v.x = fmaxf(acc[i][j].x + bv[j].x, 0.f);
                v.y = fmaxf(acc[i][j].y + bv[j].y, 0.f);
                v.z = fmaxf(acc[i][j].z + bv[j].z, 0.f);
                v.w = fmaxf(acc[i][j].w + bv[j].w, 0.f);
                *(float4*)&out[(size_t)r * D + tx16 + j * 4] = v;
                if (outh) {
                    ushort4 u = make_ushort4(f2b(v.x), f2b(v.y), f2b(v.z), f2b(v.w));
                    *(ushort4*)&outh[(size_t)r * D + tx16 + j * 4] = u;
                }
            }
        }
    }
}

// ---------------- Wc = W_m1 @ W_out ; bc = b_m1 @ W_out + b_out ----------------
__global__ __launch_bounds__(256) void smallmm_kernel(const float* __restrict__ Wm1,
                                                      const float* __restrict__ bm1,
                                                      const float* __restrict__ Wout,
                                                      const float* __restrict__ bout,
                                                      float* __restrict__ Wc,
                                                      float* __restrict__ bc) {
    int idx = blockIdx.x * 256 + threadIdx.x;
    if (blockIdx.x < 64) {
        int i = idx >> 7, j = idx & 127;
        float s = 0.f;
        for (int k = 0; k < 128; ++k) s += Wm1[i * 128 + k] * Wout[k * 128 + j];
        Wc[idx] = s;
    } else {
        int j = threadIdx.x;
        if (j < 128) {
            float s = bout[j];
            for (int k = 0; k < 128; ++k) s += bm1[k] * Wout[k * 128 + j];
            bc[j] = s;
        }
    }
}

// ---------------- s = h2@Wc + bc, softmax -> probs (+bf16 copy); den accum ----------------
__global__ __launch_bounds__(256) void out_softmax_kernel(const float* __restrict__ h2,
                                                          const float* __restrict__ Wc,
                                                          const float* __restrict__ bc,
                                                          const float* __restrict__ deg,
                                                          float* __restrict__ probs,
                                                          unsigned short* __restrict__ pbh,
                                                          float* __restrict__ accum, int N) {
    __shared__ float Rs[32][128];
    __shared__ float Ws[128 * 64];
    int tid = threadIdx.x;
    int wave = tid >> 6, lane = tid & 63;
    int r0 = blockIdx.x * 32;
#pragma unroll
    for (int i = 0; i < 4; ++i) {
        int f4 = tid + i * 256;
        int row = f4 >> 5;
        int c4 = f4 & 31;
        float4 v = make_float4(0.f, 0.f, 0.f, 0.f);
        if (r0 + row < N) v = *(const float4*)&h2[(size_t)(r0 + row) * D + c4 * 4];
        *(float4*)&Rs[row][c4 * 4] = v;
    }
    float lg[8][2];
#pragma unroll
    for (int h = 0; h < 2; ++h) {
        __syncthreads();
#pragma unroll
        for (int i = 0; i < 8; ++i) {
            int f4 = tid + i * 256;
            int k = f4 >> 4;
            int c4 = f4 & 15;
            *(float4*)&Ws[k * 64 + c4 * 4] = *(const float4*)&Wc[(size_t)k * 128 + h * 64 + c4 * 4];
        }
        __syncthreads();
        float bv = bc[h * 64 + lane];
        float a[8];
#pragma unroll
        for (int ri = 0; ri < 8; ++ri) a[ri] = bv;
        for (int k = 0; k < 128; ++k) {
            float wv = Ws[k * 64 + lane];
#pragma unroll
            for (int ri = 0; ri < 8; ++ri) a[ri] += Rs[wave + ri * 4][k] * wv;
        }
#pragma unroll
        for (int ri = 0; ri < 8; ++ri) lg[ri][h] = a[ri];
    }
    float den_local = 0.f;
#pragma unroll
    for (int ri = 0; ri < 8; ++ri) {
        int row = wave + ri * 4;
        int gr = r0 + row;
        float m = fmaxf(lg[ri][0], lg[ri][1]);
#pragma unroll
        for (int s = 32; s >= 1; s >>= 1) m = fmaxf(m, __shfl_xor(m, s));
        float e0 = expf(lg[ri][0] - m);
        float e1 = expf(lg[ri][1] - m);
        float sum = e0 + e1;
#pragma unroll
        for (int s = 32; s >= 1; s >>= 1) sum += __shfl_xor(sum, s);
        float inv = 1.f / sum;
        float p0 = e0 * inv, p1 = e1 * inv;
        float sq = p0 * p0 + p1 * p1;
#pragma unroll
        for (int s = 32; s >= 1; s >>= 1) sq += __shfl_xor(sq, s);
        if (gr < N) {
            probs[(size_t)gr * D + lane]      = p0;
            probs[(size_t)gr * D + 64 + lane] = p1;
            pbh[(size_t)gr * D + lane]      = f2b(p0);
            pbh[(size_t)gr * D + 64 + lane] = f2b(p1);
            if (lane == 0) den_local += deg[gr] * sq;
        }
    }
    if (lane == 0 && den_local != 0.f) atomicAdd(&accum[1], den_local);
}

// ---------------- merged: ss partials (blocks [0,SS_BLOCKS)) + mincut_num (rest) ----------------
__global__ __launch_bounds__(256) void num_ss_kernel(const float* __restrict__ probs,
                                                     const unsigned short* __restrict__ pbh,
                                                     const int* __restrict__ csr_src,
                                                     const float* __restrict__ csr_w,
                                                     const int* __restrict__ rowptr,
                                                     float* __restrict__ accum,
                                                     float* __restrict__ partial, int N) {
    int tid = threadIdx.x;
    if (blockIdx.x < SS_BLOCKS) {
        __shared__ float Ps[32][132];
        int a0 = (tid >> 4) * 8;
        int b0 = (tid & 15) * 8;
        float acc[8][8];
#pragma unroll
        for (int i = 0; i < 8; ++i)
#pragma unroll
            for (int j = 0; j < 8; ++j) acc[i][j] = 0.f;

        int rowsPerBlk = (N + SS_BLOCKS - 1) / SS_BLOCKS;
        int rbeg = blockIdx.x * rowsPerBlk;
        int rend = rbeg + rowsPerBlk;
        if (rend > N) rend = N;

        for (int c = rbeg; c < rend; c += 32) {
            int nr = rend - c;
            if (nr > 32) nr = 32;
            __syncthreads();
            for (int i = tid; i < nr * 32; i += 256) {
                int r = i >> 5, c4 = i & 31;
                *(float4*)&Ps[r][c4 * 4] = *(const float4*)&probs[(size_t)(c + r) * D + c4 * 4];
            }
            __syncthreads();
            for (int r = 0; r < nr; ++r) {
                float4 av0 = *(const float4*)&Ps[r][a0];
                float4 av1 = *(const float4*)&Ps[r][a0 + 4];
                float4 bv0 = *(const float4*)&Ps[r][b0];
                float4 bv1 = *(const float4*)&Ps[r][b0 + 4];
                float av[8] = {av0.x, av0.y, av0.z, av0.w, av1.x, av1.y, av1.z, av1.w};
                float bv[8] = {bv0.x, bv0.y, bv0.z, bv0.w, bv1.x, bv1.y, bv1.z, bv1.w};
#pragma unroll
                for (int i = 0; i < 8; ++i)
#pragma unroll
                    for (int j = 0; j < 8; ++j) acc[i][j] += av[i] * bv[j];
            }
        }
        float* pb = partial + (size_t)blockIdx.x * 16384;
#pragma unroll
        for (int i = 0; i < 8; ++i) {
            *(float4*)&pb[(a0 + i) * 128 + b0]     = make_float4(acc[i][0], acc[i][1], acc[i][2], acc[i][3]);
            *(float4*)&pb[(a0 + i) * 128 + b0 + 4] = make_float4(acc[i][4], acc[i][5], acc[i][6], acc[i][7]);
        }
        return;
    }
    // ---- num part: quarter-wave, 16 edges in flight ----
    int bid = blockIdx.x - SS_BLOCKS;
    int wave = tid >> 6, lane = tid & 63;
    int q = lane >> 4;
    int c8 = (lane & 15) * 8;
    float acc = 0.f;
    int stride = NUM_BLOCKS * 4;
    for (int node = bid * 4 + wave; node < N; node += stride) {
        float4 pdA = *(const float4*)&probs[(size_t)node * D + c8];
        float4 pdB = *(const float4*)&probs[(size_t)node * D + c8 + 4];
        int beg = rowptr[node], end = rowptr[node + 1];
        int j = beg;
        for (; j + 15 < end; j += 16) {
            int si[4]; float wi[4]; uint4 qv[4];
#pragma unroll
            for (int i = 0; i < 4; ++i) {
                int e = j + 4 * i + q;
                si[i] = csr_src[e];
                wi[i] = csr_w[e];
            }
#pragma unroll
            for (int i = 0; i < 4; ++i) qv[i] = *(const uint4*)&pbh[(size_t)si[i] * D + c8];
#pragma unroll
            for (int i = 0; i < 4; ++i) {
                acc += wi[i] * (bfl(qv[i].x) * pdA.x + bfh(qv[i].x) * pdA.y
                              + bfl(qv[i].y) * pdA.z + bfh(qv[i].y) * pdA.w
                              + bfl(qv[i].z) * pdB.x + bfh(qv[i].z) * pdB.y
                              + bfl(qv[i].w) * pdB.z + bfh(qv[i].w) * pdB.w);
            }
        }
        for (; j + 3 < end; j += 4) {
            int e = j + q;
            int s0 = csr_src[e]; float w0 = csr_w[e];
            uint4 qv = *(const uint4*)&pbh[(size_t)s0 * D + c8];
            acc += w0 * (bfl(qv.x) * pdA.x + bfh(qv.x) * pdA.y
                       + bfl(qv.y) * pdA.z + bfh(qv.y) * pdA.w
                       + bfl(qv.z) * pdB.x + bfh(qv.z) * pdB.y
                       + bfl(qv.w) * pdB.z + bfh(qv.w) * pdB.w);
        }
        int rem = end - j;
        if (q < rem) {
            int e = j + q;
            int s0 = csr_src[e]; float w0 = csr_w[e];
            uint4 qv = *(const uint4*)&pbh[(size_t)s0 * D + c8];
            acc += w0 * (bfl(qv.x) * pdA.x + bfh(qv.x) * pdA.y
                       + bfl(qv.y) * pdA.z + bfh(qv.y) * pdA.w
                       + bfl(qv.z) * pdB.x + bfh(qv.z) * pdB.y
                       + bfl(qv.w) * pdB.z + bfh(qv.w) * pdB.w);
        }
    }
#pragma unroll
    for (int m = 32; m >= 1; m >>= 1) acc += __shfl_xor(acc, m);
    if (lane == 0 && acc != 0.f) atomicAdd(&accum[0], acc);
}

// ---------------- reduce partials -> ss ----------------
__global__ __launch_bounds__(256) void ss_reduce_kernel(const float* __restrict__ partial,
                                                        float* __restrict__ ss) {
    int i = blockIdx.x * 256 + threadIdx.x;
    float s = 0.f;
    for (int b = 0; b < SS_BLOCKS; ++b) s += partial[(size_t)b * 16384 + i];
    ss[i] = s;
}

// ---------------- finalize: mc_loss, o_loss ----------------
__global__ __launch_bounds__(256) void finalize_kernel(const float* __restrict__ ss,
                                                       const float* __restrict__ accum,
                                                       float* __restrict__ out2) {
    int tid = threadIdx.x;
    __shared__ float wsum[4], wsum2[4];
    float s = 0.f;
    for (int i = tid; i < 16384; i += 256) { float v = ss[i]; s += v * v; }
#pragma unroll
    for (int m = 32; m >= 1; m >>= 1) s += __shfl_xor(s, m);
    if ((tid & 63) == 0) wsum[tid >> 6] = s;
    __syncthreads();
    float norm = sqrtf(wsum[0] + wsum[1] + wsum[2] + wsum[3]);
    float inv = 1.f / norm;
    const float rk = 0.08838834764831845f;  // 1/sqrt(128)
    float o = 0.f;
    for (int i = tid; i < 16384; i += 256) {
        int a = i >> 7, b = i & 127;
        float v = ss[i] * inv - (a == b ? rk : 0.f);
        o += v * v;
    }
#pragma unroll
    for (int m = 32; m >= 1; m >>= 1) o += __shfl_xor(o, m);
    if ((tid & 63) == 0) wsum2[tid >> 6] = o;
    __syncthreads();
    if (tid == 0) {
        out2[0] = -(accum[0] / accum[1]);
        out2[1] = sqrtf(wsum2[0] + wsum2[1] + wsum2[2] + wsum2[3]);
    }
}

extern "C" void kernel_launch(void* const* d_in, const int* in_sizes, int n_in,
                              void* d_out, int out_size, void* d_ws, size_t ws_size,
                              hipStream_t stream) {
    const float* x      = (const float*)d_in[0];
    const int*   ei     = (const int*)d_in[1];
    const float* w      = (const float*)d_in[2];
    const float* Wrel1  = (const float*)d_in[3];
    const float* brel1  = (const float*)d_in[4];
    const float* Wroot1 = (const float*)d_in[5];
    const float* Wrel2  = (const float*)d_in[6];
    const float* brel2  = (const float*)d_in[7];
    const float* Wroot2 = (const float*)d_in[8];
    const float* Wm1    = (const float*)d_in[9];
    const float* bm1    = (const float*)d_in[10];
    const float* Wout   = (const float*)d_in[11];
    const float* bout   = (const float*)d_in[12];

    int N = in_sizes[0] / D;
    int E = in_sizes[2];
    const int* src = ei;
    const int* dst = ei + E;

    float* probs = (float*)d_out;
    float* out2  = probs + (size_t)N * D;  // [mc_loss, o_loss]
    float* h2    = probs;                  // h2 in-place in d_out

    float* ws    = (float*)d_ws;
    float* agg   = ws;                       // N*D  (reused as ss partials)
    float* h1    = ws + (size_t)N * D;       // N*D  (aliases xh pre-lin1)
    float* Wc    = ws + (size_t)2 * N * D;   // 16384
    float* bc    = Wc + 16384;               // 128
    float* ssb   = bc + 128;                 // 16384
    float* deg   = ssb + 16384;              // N
    float* accum = deg + N;                  // 2
    float* csr_w = accum + 2;                // E
    int*   cnt   = (int*)(csr_w + E);        // N
    int*   rowptr= cnt + N;                  // N+1
    int*   aux   = rowptr + N + 1;           // 64
    int*   csr_src = aux + 64;               // E
    int*   slot  = csr_src + E;              // E
    // pbh double-duty: h1-bf16 table (lin1 -> gatherq2), then probs-bf16
    // (out_softmax -> num). Live ranges don't overlap.
    unsigned short* pbh = (unsigned short*)(slot + E);  // N*D bf16
    unsigned short* xh  = (unsigned short*)h1;          // N*D bf16 (h1 dead pre-lin1)

    hipMemsetAsync(deg, 0, (size_t)(N + 2) * sizeof(float), stream);
    hipMemsetAsync(cnt, 0, (size_t)N * sizeof(int), stream);

    int eGrid = (E + 255) / 256;
    int nb = (N + 1023) / 1024;
    int n8 = N * D / 8;
    int fGrid = (n8 + 255) / 256;

    // merged f2bf + hist/deg/slot
    pre_kernel<<<fGrid + eGrid, 256, 0, stream>>>(x, xh, src, dst, w, cnt, deg, slot,
                                                  E, n8, fGrid);
    scan_chunk_kernel<<<nb, 256, 0, stream>>>(cnt, rowptr, aux, N);
    scan_aux_kernel<<<1, 64, 0, stream>>>(aux, nb);
    add_off_kernel<<<(N + 255) / 256, 256, 0, stream>>>(rowptr, aux, N);
    fill_kernel<<<eGrid, 256, 0, stream>>>(src, dst, w, rowptr, slot, csr_src, csr_w, E);

    // layer 1: bf16 gather + linear (emits h1 fp32 + h1 bf16 table into pbh)
    gatherq_kernel<<<(N + 3) / 4, 256, 0, stream>>>(xh, csr_src, csr_w, rowptr, agg, N);
    lin_kernel<<<(N + 127) / 128, 256, 0, stream>>>(agg, x, Wrel1, Wroot1, brel1,
                                                    h1, pbh, N);
    // layer 2: bf16 gather (pbh as h1-bf16) + linear (h2 in-place in probs)
    gatherq_kernel<<<(N + 3) / 4, 256, 0, stream>>>(pbh, csr_src, csr_w, rowptr, agg, N);
    lin_kernel<<<(N + 127) / 128, 256, 0, stream>>>(agg, h1, Wrel2, Wroot2, brel2,
                                                    h2, (unsigned short*)nullptr, N);
    smallmm_kernel<<<65, 256, 0, stream>>>(Wm1, bm1, Wout, bout, Wc, bc);
    out_softmax_kernel<<<(N + 31) / 32, 256, 0, stream>>>(h2, Wc, bc, deg, probs, pbh, accum, N);
    num_ss_kernel<<<SS_BLOCKS + NUM_BLOCKS, 256, 0, stream>>>(probs, pbh, csr_src, csr_w,
                                                              rowptr, accum, agg, N);
    ss_reduce_kernel<<<64, 256, 0, stream>>>(agg, ssb);
    finalize_kernel<<<1, 256, 0, stream>>>(ssb, accum, out2);
}